// Round 1
// baseline (1738.980 us; speedup 1.0000x reference)
//
#include <hip/hip_runtime.h>
#include <math.h>

// TransitionNER head:  hidden = tanh(concat(4x[B,1024]) @ W1 + b1)
//                      logits = hidden @ W2 + b2 ; masked log-softmax ; argmax + gold gather
// B=16384, H=1024, A=20, K=4096.
//
// Round 0: correctness-first full-f32 implementation.
//  - GEMM1: 128x128x8 f32 SGEMM tile, 256 thr, 8x8/thread, LDS staged, reg prefetch.
//  - head:  one wave64 per row, butterfly reduce of 20 partial dots.
//  - valid_mask dtype unknown (bool->u8/int32/float32?) -> byte-pattern detection kernel.
//  - hidden lives in d_ws, chunked over B if ws_size is small.

#define BTOT 16384
#define HD   1024
#define NACT 20
#define KTOT 4096

// ---------------- mask dtype detection ----------------
// Counts nonzero bytes at each (offset % 4) over the first B*A bytes of the
// mask buffer (safe under every dtype interpretation: u8 buffer is exactly
// B*A bytes; i32/f32 buffers are 4x larger).
//   u8 bool : nonzero bytes at all offsets          -> c1 > 0
//   f32 0/1 : 1.0f = 00 00 80 3F -> c2,c3 > 0, c1=0 -> c3 > 0
//   i32 0/1 : only byte0 nonzero                    -> else
__global__ __launch_bounds__(256) void detect_mask_kernel(
    const unsigned int* __restrict__ w, int nwords, int* __restrict__ ctr)
{
    int c0 = 0, c1 = 0, c2 = 0, c3 = 0;
    for (int i = blockIdx.x * 256 + threadIdx.x; i < nwords; i += gridDim.x * 256) {
        unsigned int v = w[i];
        c0 += (v & 0x000000FFu) ? 1 : 0;
        c1 += (v & 0x0000FF00u) ? 1 : 0;
        c2 += (v & 0x00FF0000u) ? 1 : 0;
        c3 += (v & 0xFF000000u) ? 1 : 0;
    }
#pragma unroll
    for (int off = 32; off; off >>= 1) {
        c0 += __shfl_xor(c0, off, 64);
        c1 += __shfl_xor(c1, off, 64);
        c2 += __shfl_xor(c2, off, 64);
        c3 += __shfl_xor(c3, off, 64);
    }
    if ((threadIdx.x & 63) == 0) {
        atomicAdd(&ctr[0], c0);
        atomicAdd(&ctr[1], c1);
        atomicAdd(&ctr[2], c2);
        atomicAdd(&ctr[3], c3);
    }
}

// ---------------- GEMM1 + bias + tanh ----------------
// grid = (8 n-tiles, rows/128 m-tiles); block = 256.
// X[i,k] = seg(k>>10)[i*1024 + (k&1023)]  (concat of 4 inputs along k)
__global__ __launch_bounds__(256) void gemm1_tanh_kernel(
    const float* __restrict__ A0, const float* __restrict__ A1,
    const float* __restrict__ A2, const float* __restrict__ A3,
    const float* __restrict__ W1, const float* __restrict__ b1,
    float* __restrict__ hidden, int rowBase)
{
    __shared__ __align__(16) float As[8][128];   // [kk][row]
    __shared__ __align__(16) float Bs[8][128];   // [kk][col]

    const int tid   = threadIdx.x;
    const int nBase = blockIdx.x * 128;          // over H
    const int mBase = blockIdx.y * 128;          // chunk-local rows

    const int tx = tid & 15;                     // 16 col-groups
    const int ty = tid >> 4;                     // 16 row-groups

    // A staging: 128 rows x 8 k, float4 over k: thread -> (row, k4)
    const int aRow = tid >> 1;
    const int aK4  = (tid & 1) * 4;
    // B staging: 8 k x 128 cols, float4 over cols
    const int bKK  = tid >> 5;
    const int bCol = (tid & 31) * 4;

    const size_t aRowOff = (size_t)(rowBase + mBase + aRow) * HD;

    float acc[8][8];
#pragma unroll
    for (int i = 0; i < 8; ++i)
#pragma unroll
        for (int j = 0; j < 8; ++j) acc[i][j] = 0.f;

    // prefetch k0 = 0 (segment 0 = A0)
    float4 av = *(const float4*)(A0 + aRowOff + aK4);
    float4 bv = *(const float4*)(W1 + (size_t)bKK * HD + nBase + bCol);

    for (int k0 = 0; k0 < KTOT; k0 += 8) {
        // store staged tile
        As[aK4 + 0][aRow] = av.x;
        As[aK4 + 1][aRow] = av.y;
        As[aK4 + 2][aRow] = av.z;
        As[aK4 + 3][aRow] = av.w;
        *(float4*)(&Bs[bKK][bCol]) = bv;
        __syncthreads();

        // prefetch next tile (clamped on last iter; harmless reload)
        const int kn = (k0 + 8 < KTOT) ? (k0 + 8) : k0;
        const float* Ain = (kn < 1024) ? A0 : (kn < 2048) ? A1 : (kn < 3072) ? A2 : A3;
        av = *(const float4*)(Ain + aRowOff + (kn & 1023) + aK4);
        bv = *(const float4*)(W1 + (size_t)(kn + bKK) * HD + nBase + bCol);

#pragma unroll
        for (int kk = 0; kk < 8; ++kk) {
            // a: rows ty*8 .. ty*8+7 (broadcast across 16 lanes -> conflict-free)
            const float4 a0 = *(const float4*)(&As[kk][ty * 8]);
            const float4 a1 = *(const float4*)(&As[kk][ty * 8 + 4]);
            // b: cols {tx*4..+3} and {64+tx*4..+3} (stride-4 groups -> conflict-free)
            const float4 b0 = *(const float4*)(&Bs[kk][tx * 4]);
            const float4 b1v = *(const float4*)(&Bs[kk][64 + tx * 4]);
            const float a[8] = {a0.x, a0.y, a0.z, a0.w, a1.x, a1.y, a1.z, a1.w};
            const float b[8] = {b0.x, b0.y, b0.z, b0.w, b1v.x, b1v.y, b1v.z, b1v.w};
#pragma unroll
            for (int i = 0; i < 8; ++i)
#pragma unroll
                for (int j = 0; j < 8; ++j)
                    acc[i][j] = fmaf(a[i], b[j], acc[i][j]);
        }
        __syncthreads();
    }

    // epilogue: bias + tanh, store hidden (chunk-local rows)
    const float4 bias0 = *(const float4*)(b1 + nBase + tx * 4);
    const float4 bias1 = *(const float4*)(b1 + nBase + 64 + tx * 4);
    const float bb[8] = {bias0.x, bias0.y, bias0.z, bias0.w,
                         bias1.x, bias1.y, bias1.z, bias1.w};
#pragma unroll
    for (int i = 0; i < 8; ++i) {
        const int row = mBase + ty * 8 + i;
        float4 o0, o1;
        o0.x = tanhf(acc[i][0] + bb[0]);
        o0.y = tanhf(acc[i][1] + bb[1]);
        o0.z = tanhf(acc[i][2] + bb[2]);
        o0.w = tanhf(acc[i][3] + bb[3]);
        o1.x = tanhf(acc[i][4] + bb[4]);
        o1.y = tanhf(acc[i][5] + bb[5]);
        o1.z = tanhf(acc[i][6] + bb[6]);
        o1.w = tanhf(acc[i][7] + bb[7]);
        *(float4*)(hidden + (size_t)row * HD + nBase + tx * 4) = o0;
        *(float4*)(hidden + (size_t)row * HD + nBase + 64 + tx * 4) = o1;
    }
}

// ---------------- head: logits, masked log-softmax, argmax, loss ----------------
// one wave64 per row; block = 256 -> 4 rows/block.
__global__ __launch_bounds__(256) void head_kernel(
    const float* __restrict__ hidden, const float* __restrict__ W2,
    const float* __restrict__ b2, const void* __restrict__ mask,
    const int* __restrict__ real_actions, const int* __restrict__ ctr,
    float* __restrict__ out, int rowBase)
{
    const int lane     = threadIdx.x & 63;
    const int localRow = blockIdx.x * 4 + (threadIdx.x >> 6);
    const int row      = rowBase + localRow;

    float acc[NACT];
#pragma unroll
    for (int a = 0; a < NACT; ++a) acc[a] = 0.f;

    const float* hrow = hidden + (size_t)localRow * HD;
#pragma unroll 4
    for (int j = 0; j < 16; ++j) {
        const int h = lane + 64 * j;
        const float hv = hrow[h];
        const float4* w4 = (const float4*)(W2 + (size_t)h * NACT);  // 80B rows, 16B-aligned
        const float4 w0 = w4[0], w1 = w4[1], w2 = w4[2], w3 = w4[3], w4v = w4[4];
        acc[0]  = fmaf(hv, w0.x,  acc[0]);  acc[1]  = fmaf(hv, w0.y,  acc[1]);
        acc[2]  = fmaf(hv, w0.z,  acc[2]);  acc[3]  = fmaf(hv, w0.w,  acc[3]);
        acc[4]  = fmaf(hv, w1.x,  acc[4]);  acc[5]  = fmaf(hv, w1.y,  acc[5]);
        acc[6]  = fmaf(hv, w1.z,  acc[6]);  acc[7]  = fmaf(hv, w1.w,  acc[7]);
        acc[8]  = fmaf(hv, w2.x,  acc[8]);  acc[9]  = fmaf(hv, w2.y,  acc[9]);
        acc[10] = fmaf(hv, w2.z,  acc[10]); acc[11] = fmaf(hv, w2.w,  acc[11]);
        acc[12] = fmaf(hv, w3.x,  acc[12]); acc[13] = fmaf(hv, w3.y,  acc[13]);
        acc[14] = fmaf(hv, w3.z,  acc[14]); acc[15] = fmaf(hv, w3.w,  acc[15]);
        acc[16] = fmaf(hv, w4v.x, acc[16]); acc[17] = fmaf(hv, w4v.y, acc[17]);
        acc[18] = fmaf(hv, w4v.z, acc[18]); acc[19] = fmaf(hv, w4v.w, acc[19]);
    }

#pragma unroll
    for (int off = 32; off; off >>= 1) {
#pragma unroll
        for (int a = 0; a < NACT; ++a) acc[a] += __shfl_xor(acc[a], off, 64);
    }

    // mask format: 0=u8, 1=i32, 2=f32
    const int c1 = ctr[1], c2 = ctr[2], c3 = ctr[3];
    const int fmt = (c1 > 0) ? 0 : ((c2 > 0 || c3 > 0) ? 2 : 1);

    float masked[NACT];
#pragma unroll
    for (int a = 0; a < NACT; ++a) {
        const float lg = acc[a] + b2[a];
        bool valid;
        if (fmt == 0)      valid = ((const unsigned char*)mask)[(size_t)row * NACT + a] != 0;
        else if (fmt == 1) valid = ((const int*)mask)[(size_t)row * NACT + a] != 0;
        else               valid = ((const float*)mask)[(size_t)row * NACT + a] != 0.f;
        masked[a] = valid ? lg : -1e9f;
    }

    // first-index argmax (matches jnp.argmax tie-break)
    float m = masked[0];
    int amax = 0;
#pragma unroll
    for (int a = 1; a < NACT; ++a) {
        if (masked[a] > m) { m = masked[a]; amax = a; }
    }
    float s = 0.f;
#pragma unroll
    for (int a = 0; a < NACT; ++a) s += expf(masked[a] - m);
    const float lse = m + logf(s);

    // gold gather without runtime array indexing (avoid scratch)
    const int ga = real_actions[row];
    float gl = masked[0];
#pragma unroll
    for (int a = 1; a < NACT; ++a) gl = (ga == a) ? masked[a] : gl;

    if (lane == 0) {
        out[row]        = (float)amax;   // predict_actions as f32
        out[BTOT + row] = gl - lse;      // losses
    }
}

// ---------------- launcher ----------------
extern "C" void kernel_launch(void* const* d_in, const int* in_sizes, int n_in,
                              void* d_out, int out_size, void* d_ws, size_t ws_size,
                              hipStream_t stream)
{
    const float* buf_h  = (const float*)d_in[0];
    const float* stk_h  = (const float*)d_in[1];
    const float* out_h  = (const float*)d_in[2];
    const float* act_h  = (const float*)d_in[3];
    const float* W1     = (const float*)d_in[4];
    const float* b1     = (const float*)d_in[5];
    const float* W2     = (const float*)d_in[6];
    const float* b2     = (const float*)d_in[7];
    const void*  mask   = d_in[8];
    const int*   ra     = (const int*)d_in[9];
    float*       out    = (float*)d_out;

    // ws layout: [0,16) mask-format counters; [256, ...) hidden chunk buffer
    int*   ctr    = (int*)d_ws;
    float* hidden = (float*)((char*)d_ws + 256);

    hipMemsetAsync(d_ws, 0, 16, stream);
    detect_mask_kernel<<<64, 256, 0, stream>>>(
        (const unsigned int*)mask, BTOT * NACT / 4, ctr);

    // chunk rows so hidden fits in the workspace (multiple of 128)
    const size_t avail = (ws_size > 256) ? (ws_size - 256) : 0;
    long maxRows = (long)(avail / ((size_t)HD * sizeof(float)));
    int Bc;
    if (maxRows >= BTOT) Bc = BTOT;
    else {
        Bc = (int)((maxRows / 128) * 128);
        if (Bc <= 0) Bc = 128;  // minimal assumption: ws_size >= ~512 KiB
    }

    for (int r0 = 0; r0 < BTOT; r0 += Bc) {
        const int rows = (BTOT - r0 < Bc) ? (BTOT - r0) : Bc;  // multiple of 128
        dim3 g1(8, rows / 128);
        gemm1_tanh_kernel<<<g1, 256, 0, stream>>>(
            buf_h, stk_h, out_h, act_h, W1, b1, hidden, r0);
        head_kernel<<<rows / 4, 256, 0, stream>>>(
            hidden, W2, b2, mask, ra, ctr, out, r0);
    }
}

// Round 2
// 1433.951 us; speedup vs baseline: 1.2127x; 1.2127x over previous
//
#include <hip/hip_runtime.h>
#include <math.h>

// TransitionNER head:  hidden = tanh(concat(4x[B,1024]) @ W1 + b1)
//                      logits = hidden @ W2 + b2 ; masked log-softmax ; argmax + gold gather
// B=16384, H=1024, A=20, K=4096.
//
// Round 2: GEMM1 on matrix cores via bf16 hi/lo split (3-pass f32 emulation,
// per-product rel err ~2^-17), plus exact-f32 refinement of rows whose
// masked top-2 logit gap < 1e-3 (expected ~90 rows) to keep argmax exact.
//  - W1 transposed+split once per launch into ws ([N][K] bf16 hi/lo).
//  - X split on the fly during LDS staging (RNE bit-trick).
//  - LDS XOR-swizzle (byte ^= (row&7)<<4): 2-way conflicts only (free, m136).
//  - mfma_f32_16x16x32_bf16; A: row=l&15,k=(l>>4)*8+j; D: col=l&15,row=(l>>4)*4+r.

#define BTOT 16384
#define HD   1024
#define NACT 20
#define KTOT 4096

typedef __attribute__((ext_vector_type(8))) short short8;
typedef __attribute__((ext_vector_type(4))) float f32x4;

#define MFMA(a, b, c) __builtin_amdgcn_mfma_f32_16x16x32_bf16((a), (b), (c), 0, 0, 0)

// ---------------- bf16 split helpers (RNE) ----------------
__device__ __forceinline__ void split8(const float4 v0, const float4 v1,
                                       int4& hi, int4& lo)
{
    const float f[8] = {v0.x, v0.y, v0.z, v0.w, v1.x, v1.y, v1.z, v1.w};
    unsigned hp[4], lp[4];
#pragma unroll
    for (int i = 0; i < 4; ++i) {
        const unsigned u0 = __float_as_uint(f[2 * i]);
        const unsigned u1 = __float_as_uint(f[2 * i + 1]);
        const unsigned r0 = u0 + 0x7FFFu + ((u0 >> 16) & 1u);
        const unsigned r1 = u1 + 0x7FFFu + ((u1 >> 16) & 1u);
        hp[i] = (r0 >> 16) | (r1 & 0xFFFF0000u);
        const float h0 = __uint_as_float(r0 & 0xFFFF0000u);
        const float h1 = __uint_as_float(r1 & 0xFFFF0000u);
        const float d0 = f[2 * i] - h0;
        const float d1 = f[2 * i + 1] - h1;
        const unsigned s0 = __float_as_uint(d0);
        const unsigned s1 = __float_as_uint(d1);
        const unsigned q0 = s0 + 0x7FFFu + ((s0 >> 16) & 1u);
        const unsigned q1 = s1 + 0x7FFFu + ((s1 >> 16) & 1u);
        lp[i] = (q0 >> 16) | (q1 & 0xFFFF0000u);
    }
    hi = make_int4((int)hp[0], (int)hp[1], (int)hp[2], (int)hp[3]);
    lo = make_int4((int)lp[0], (int)lp[1], (int)lp[2], (int)lp[3]);
}

// ---------------- mask dtype detection ----------------
__global__ __launch_bounds__(256) void detect_mask_kernel(
    const unsigned int* __restrict__ w, int nwords, int* __restrict__ ctr)
{
    int c0 = 0, c1 = 0, c2 = 0, c3 = 0;
    for (int i = blockIdx.x * 256 + threadIdx.x; i < nwords; i += gridDim.x * 256) {
        unsigned int v = w[i];
        c0 += (v & 0x000000FFu) ? 1 : 0;
        c1 += (v & 0x0000FF00u) ? 1 : 0;
        c2 += (v & 0x00FF0000u) ? 1 : 0;
        c3 += (v & 0xFF000000u) ? 1 : 0;
    }
#pragma unroll
    for (int off = 32; off; off >>= 1) {
        c0 += __shfl_xor(c0, off, 64);
        c1 += __shfl_xor(c1, off, 64);
        c2 += __shfl_xor(c2, off, 64);
        c3 += __shfl_xor(c3, off, 64);
    }
    if ((threadIdx.x & 63) == 0) {
        atomicAdd(&ctr[0], c0);
        atomicAdd(&ctr[1], c1);
        atomicAdd(&ctr[2], c2);
        atomicAdd(&ctr[3], c3);
    }
}

// ---------------- W1 transpose + hi/lo split:  [K][N] f32 -> [N][K] bf16 x2 ----------------
__global__ __launch_bounds__(256) void w1_split_kernel(
    const float* __restrict__ W1,
    unsigned short* __restrict__ Bh, unsigned short* __restrict__ Bl)
{
    __shared__ float tile[64][65];
    const int k0 = blockIdx.x * 64;
    const int n0 = blockIdx.y * 64;
    const int tid = threadIdx.x;
#pragma unroll
    for (int i = 0; i < 16; ++i) {
        const int idx = i * 256 + tid;
        const int kk = idx >> 6, nn = idx & 63;
        tile[kk][nn] = W1[(size_t)(k0 + kk) * HD + n0 + nn];
    }
    __syncthreads();
#pragma unroll
    for (int i = 0; i < 16; ++i) {
        const int idx = i * 256 + tid;
        const int nn = idx >> 6, kk = idx & 63;
        const float v = tile[kk][nn];
        const unsigned u = __float_as_uint(v);
        const unsigned r = u + 0x7FFFu + ((u >> 16) & 1u);
        const float hf = __uint_as_float(r & 0xFFFF0000u);
        const float d = v - hf;
        const unsigned ud = __float_as_uint(d);
        const unsigned rd = ud + 0x7FFFu + ((ud >> 16) & 1u);
        const size_t o = (size_t)(n0 + nn) * KTOT + k0 + kk;
        Bh[o] = (unsigned short)(r >> 16);
        Bl[o] = (unsigned short)(rd >> 16);
    }
}

// ---------------- GEMM1 (MFMA, 3-pass split) + bias + tanh ----------------
// grid = (8 n-tiles, rows/128 m-tiles); 256 thr = 4 waves (2x2 of 64x64).
#define AHI 0
#define ALO 16384
#define BHI 32768
#define BLO 49152

__global__ __launch_bounds__(256, 2) void gemm1_mfma_kernel(
    const float* __restrict__ A0, const float* __restrict__ A1,
    const float* __restrict__ A2, const float* __restrict__ A3,
    const unsigned short* __restrict__ Bh, const unsigned short* __restrict__ Bl,
    const float* __restrict__ b1, float* __restrict__ hidden, int rowBase)
{
    __shared__ __align__(16) unsigned char smem[65536];

    const int tid   = threadIdx.x;
    const int nBase = blockIdx.x * 128;
    const int mBase = blockIdx.y * 128;

    const int lane = tid & 63;
    const int wid  = tid >> 6;
    const int wr = wid >> 1, wc = wid & 1;
    const int lrow = lane & 15;
    const int lkc  = lane >> 4;                       // k-chunk within a 32-k slice
    const unsigned xv = (unsigned)(lane & 7) << 4;    // row XOR (row&7 == lane&7 for frag rows)

    // staging: thread -> (row 0..127, 32-elem half of the 64-k tile)
    const int sRow = tid >> 1;
    const int sSel = tid & 1;
    const size_t aOff = (size_t)(rowBase + mBase + sRow) * HD + sSel * 32;
    const unsigned short* bhBase = Bh + (size_t)(nBase + sRow) * KTOT + sSel * 32;
    const unsigned short* blBase = Bl + (size_t)(nBase + sRow) * KTOT + sSel * 32;

    unsigned wOff[4];
#pragma unroll
    for (int c = 0; c < 4; ++c)
        wOff[c] = (unsigned)sRow * 128 +
                  ((((unsigned)(sSel * 4 + c)) * 16) ^ (((unsigned)sRow & 7u) << 4));

    const unsigned aBase = (unsigned)(wr * 64 + lrow) * 128;
    const unsigned bBase = (unsigned)(wc * 64 + lrow) * 128;

    f32x4 acc[4][4];
#pragma unroll
    for (int i = 0; i < 4; ++i)
#pragma unroll
        for (int j = 0; j < 4; ++j) acc[i][j] = (f32x4){0.f, 0.f, 0.f, 0.f};

    // prefetch kt = 0
    float4 aF[8];
    int4 bHv[4], bLv[4];
    {
        const float4* ap = (const float4*)(A0 + aOff);
#pragma unroll
        for (int i = 0; i < 8; ++i) aF[i] = ap[i];
        const int4* bhp = (const int4*)(bhBase);
        const int4* blp = (const int4*)(blBase);
#pragma unroll
        for (int i = 0; i < 4; ++i) { bHv[i] = bhp[i]; bLv[i] = blp[i]; }
    }

    for (int kt = 0; kt < 64; ++kt) {
        // ---- stage into LDS (convert A f32 -> bf16 hi/lo) ----
#pragma unroll
        for (int c = 0; c < 4; ++c) {
            int4 hi, lo;
            split8(aF[2 * c], aF[2 * c + 1], hi, lo);
            *(int4*)(smem + AHI + wOff[c]) = hi;
            *(int4*)(smem + ALO + wOff[c]) = lo;
        }
#pragma unroll
        for (int c = 0; c < 4; ++c) {
            *(int4*)(smem + BHI + wOff[c]) = bHv[c];
            *(int4*)(smem + BLO + wOff[c]) = bLv[c];
        }
        __syncthreads();

        // ---- prefetch next K-tile (overlaps with MFMA below) ----
        {
            const int kn = ((kt < 63) ? (kt + 1) : kt) * 64;
            const float* seg = (kn < 1024) ? A0 : (kn < 2048) ? A1 : (kn < 3072) ? A2 : A3;
            const float4* ap = (const float4*)(seg + aOff + (kn & 1023));
#pragma unroll
            for (int i = 0; i < 8; ++i) aF[i] = ap[i];
            const int4* bhp = (const int4*)(bhBase + kn);
            const int4* blp = (const int4*)(blBase + kn);
#pragma unroll
            for (int i = 0; i < 4; ++i) { bHv[i] = bhp[i]; bLv[i] = blp[i]; }
        }

        // ---- compute: 2 k-slices x 16 frag pairs x 3 passes ----
#pragma unroll
        for (int ks = 0; ks < 2; ++ks) {
            const unsigned co = (((unsigned)(ks * 4 + lkc)) * 16) ^ xv;
            short8 ah[4], al[4], bh[4], bl[4];
#pragma unroll
            for (int f = 0; f < 4; ++f) {
                ah[f] = *(const short8*)(smem + AHI + aBase + f * 2048 + co);
                al[f] = *(const short8*)(smem + ALO + aBase + f * 2048 + co);
                bh[f] = *(const short8*)(smem + BHI + bBase + f * 2048 + co);
                bl[f] = *(const short8*)(smem + BLO + bBase + f * 2048 + co);
            }
#pragma unroll
            for (int fi = 0; fi < 4; ++fi)
#pragma unroll
                for (int fj = 0; fj < 4; ++fj) {
                    acc[fi][fj] = MFMA(ah[fi], bh[fj], acc[fi][fj]);
                    acc[fi][fj] = MFMA(ah[fi], bl[fj], acc[fi][fj]);
                    acc[fi][fj] = MFMA(al[fi], bh[fj], acc[fi][fj]);
                }
        }
        __syncthreads();
    }

    // ---- epilogue: bias + tanh ----
#pragma unroll
    for (int fj = 0; fj < 4; ++fj) {
        const int col = nBase + wc * 64 + fj * 16 + lrow;
        const float bias = b1[col];
#pragma unroll
        for (int fi = 0; fi < 4; ++fi) {
            const int row0 = mBase + wr * 64 + fi * 16 + lkc * 4;
#pragma unroll
            for (int r = 0; r < 4; ++r)
                hidden[(size_t)(row0 + r) * HD + col] = tanhf(acc[fi][fj][r] + bias);
        }
    }
}

// ---------------- shared head/refine epilogue ----------------
__device__ __forceinline__ void finish_row(
    const float* __restrict__ acc, const float* __restrict__ b2,
    const void* __restrict__ mask, const int* __restrict__ real_actions,
    int fmt, int row, float* __restrict__ out,
    int* __restrict__ flagCnt, int* __restrict__ flagList, int lane)
{
    float masked[NACT];
#pragma unroll
    for (int a = 0; a < NACT; ++a) {
        const float lg = acc[a] + b2[a];
        bool valid;
        if (fmt == 0)      valid = ((const unsigned char*)mask)[(size_t)row * NACT + a] != 0;
        else if (fmt == 1) valid = ((const int*)mask)[(size_t)row * NACT + a] != 0;
        else               valid = ((const float*)mask)[(size_t)row * NACT + a] != 0.f;
        masked[a] = valid ? lg : -1e9f;
    }
    float m = masked[0], m2 = -3e38f;
    int amax = 0;
#pragma unroll
    for (int a = 1; a < NACT; ++a) {
        const float v = masked[a];
        if (v > m) { m2 = m; m = v; amax = a; }
        else if (v > m2) m2 = v;
    }
    float s = 0.f;
#pragma unroll
    for (int a = 0; a < NACT; ++a) s += expf(masked[a] - m);
    const float lse = m + logf(s);
    const int ga = real_actions[row];
    float gl = masked[0];
#pragma unroll
    for (int a = 1; a < NACT; ++a) gl = (ga == a) ? masked[a] : gl;
    if (lane == 0) {
        out[row] = (float)amax;
        out[BTOT + row] = gl - lse;
        if (flagList != nullptr && (m - m2) < 1e-3f) {
            const int ix = atomicAdd(flagCnt, 1);
            flagList[ix] = row;
        }
    }
}

// ---------------- head: logits, masked log-softmax, argmax, loss, gap-flag ----------------
__global__ __launch_bounds__(256) void head_kernel(
    const float* __restrict__ hidden, const float* __restrict__ W2,
    const float* __restrict__ b2, const void* __restrict__ mask,
    const int* __restrict__ real_actions, int* __restrict__ ctr,
    int* __restrict__ flagList, float* __restrict__ out, int rowBase)
{
    const int lane     = threadIdx.x & 63;
    const int localRow = blockIdx.x * 4 + (threadIdx.x >> 6);
    const int row      = rowBase + localRow;

    float acc[NACT];
#pragma unroll
    for (int a = 0; a < NACT; ++a) acc[a] = 0.f;

    const float* hrow = hidden + (size_t)localRow * HD;
#pragma unroll 4
    for (int j = 0; j < 16; ++j) {
        const int h = lane + 64 * j;
        const float hv = hrow[h];
        const float4* w4 = (const float4*)(W2 + (size_t)h * NACT);
        const float4 w0 = w4[0], w1 = w4[1], w2 = w4[2], w3 = w4[3], w4v = w4[4];
        acc[0]  = fmaf(hv, w0.x,  acc[0]);  acc[1]  = fmaf(hv, w0.y,  acc[1]);
        acc[2]  = fmaf(hv, w0.z,  acc[2]);  acc[3]  = fmaf(hv, w0.w,  acc[3]);
        acc[4]  = fmaf(hv, w1.x,  acc[4]);  acc[5]  = fmaf(hv, w1.y,  acc[5]);
        acc[6]  = fmaf(hv, w1.z,  acc[6]);  acc[7]  = fmaf(hv, w1.w,  acc[7]);
        acc[8]  = fmaf(hv, w2.x,  acc[8]);  acc[9]  = fmaf(hv, w2.y,  acc[9]);
        acc[10] = fmaf(hv, w2.z,  acc[10]); acc[11] = fmaf(hv, w2.w,  acc[11]);
        acc[12] = fmaf(hv, w3.x,  acc[12]); acc[13] = fmaf(hv, w3.y,  acc[13]);
        acc[14] = fmaf(hv, w3.z,  acc[14]); acc[15] = fmaf(hv, w3.w,  acc[15]);
        acc[16] = fmaf(hv, w4v.x, acc[16]); acc[17] = fmaf(hv, w4v.y, acc[17]);
        acc[18] = fmaf(hv, w4v.z, acc[18]); acc[19] = fmaf(hv, w4v.w, acc[19]);
    }
#pragma unroll
    for (int off = 32; off; off >>= 1) {
#pragma unroll
        for (int a = 0; a < NACT; ++a) acc[a] += __shfl_xor(acc[a], off, 64);
    }

    const int c1 = ctr[1], c2 = ctr[2], c3 = ctr[3];
    const int fmt = (c1 > 0) ? 0 : ((c2 > 0 || c3 > 0) ? 2 : 1);

    finish_row(acc, b2, mask, real_actions, fmt, row, out, &ctr[4], flagList, lane);
}

// ---------------- exact-f32 refinement of flagged rows (4 rows / block) ----------------
__global__ __launch_bounds__(256) void refine_kernel(
    const float* __restrict__ A0, const float* __restrict__ A1,
    const float* __restrict__ A2, const float* __restrict__ A3,
    const float* __restrict__ W1, const float* __restrict__ b1,
    const float* __restrict__ W2, const float* __restrict__ b2,
    const void* __restrict__ mask, const int* __restrict__ real_actions,
    const int* __restrict__ ctr, const int* __restrict__ list,
    float* __restrict__ out)
{
    __shared__ float xs[4][KTOT];   // 64 KiB, reused for hidden rows after k-loop
    const int tid = threadIdx.x;
    const int count = ctr[4];
    const int c1 = ctr[1], c2 = ctr[2], c3 = ctr[3];
    const int fmt = (c1 > 0) ? 0 : ((c2 > 0 || c3 > 0) ? 2 : 1);

    for (int base = blockIdx.x * 4; base < count; base += gridDim.x * 4) {
        const int nr = min(count - base, 4);
        for (int j = 0; j < nr; ++j) {
            const int row = list[base + j];
            for (int i = tid; i < KTOT; i += 256) {
                const float* seg = (i < 1024) ? A0 : (i < 2048) ? A1 : (i < 3072) ? A2 : A3;
                xs[j][i] = seg[(size_t)row * HD + (i & 1023)];
            }
        }
        __syncthreads();

        const int c0 = tid * 4;
        float acc[4][4];
#pragma unroll
        for (int j = 0; j < 4; ++j)
#pragma unroll
            for (int i = 0; i < 4; ++i) acc[j][i] = 0.f;

        for (int k = 0; k < KTOT; ++k) {
            const float4 w = *(const float4*)(W1 + (size_t)k * HD + c0);
#pragma unroll
            for (int j = 0; j < 4; ++j) {
                const float x = xs[j][k];
                acc[j][0] = fmaf(x, w.x, acc[j][0]);
                acc[j][1] = fmaf(x, w.y, acc[j][1]);
                acc[j][2] = fmaf(x, w.z, acc[j][2]);
                acc[j][3] = fmaf(x, w.w, acc[j][3]);
            }
        }
        __syncthreads();

        float* hs = &xs[0][0];      // [4][HD]
        const float4 bb = *(const float4*)(b1 + c0);
#pragma unroll
        for (int j = 0; j < 4; ++j) {
            hs[(size_t)j * HD + c0 + 0] = tanhf(acc[j][0] + bb.x);
            hs[(size_t)j * HD + c0 + 1] = tanhf(acc[j][1] + bb.y);
            hs[(size_t)j * HD + c0 + 2] = tanhf(acc[j][2] + bb.z);
            hs[(size_t)j * HD + c0 + 3] = tanhf(acc[j][3] + bb.w);
        }
        __syncthreads();

        const int j = tid >> 6, lane = tid & 63;
        if (j < nr) {
            const int row = list[base + j];
            float a20[NACT];
#pragma unroll
            for (int a = 0; a < NACT; ++a) a20[a] = 0.f;
#pragma unroll 4
            for (int m = 0; m < 16; ++m) {
                const int h = lane + 64 * m;
                const float hv = hs[(size_t)j * HD + h];
                const float4* w4 = (const float4*)(W2 + (size_t)h * NACT);
                const float4 w0 = w4[0], w1 = w4[1], w2 = w4[2], w3 = w4[3], w4v = w4[4];
                a20[0]  = fmaf(hv, w0.x,  a20[0]);  a20[1]  = fmaf(hv, w0.y,  a20[1]);
                a20[2]  = fmaf(hv, w0.z,  a20[2]);  a20[3]  = fmaf(hv, w0.w,  a20[3]);
                a20[4]  = fmaf(hv, w1.x,  a20[4]);  a20[5]  = fmaf(hv, w1.y,  a20[5]);
                a20[6]  = fmaf(hv, w1.z,  a20[6]);  a20[7]  = fmaf(hv, w1.w,  a20[7]);
                a20[8]  = fmaf(hv, w2.x,  a20[8]);  a20[9]  = fmaf(hv, w2.y,  a20[9]);
                a20[10] = fmaf(hv, w2.z,  a20[10]); a20[11] = fmaf(hv, w2.w,  a20[11]);
                a20[12] = fmaf(hv, w3.x,  a20[12]); a20[13] = fmaf(hv, w3.y,  a20[13]);
                a20[14] = fmaf(hv, w3.z,  a20[14]); a20[15] = fmaf(hv, w3.w,  a20[15]);
                a20[16] = fmaf(hv, w4v.x, a20[16]); a20[17] = fmaf(hv, w4v.y, a20[17]);
                a20[18] = fmaf(hv, w4v.z, a20[18]); a20[19] = fmaf(hv, w4v.w, a20[19]);
            }
#pragma unroll
            for (int off = 32; off; off >>= 1) {
#pragma unroll
                for (int a = 0; a < NACT; ++a) a20[a] += __shfl_xor(a20[a], off, 64);
            }
            finish_row(a20, b2, mask, real_actions, fmt, row, out, nullptr, nullptr, lane);
        }
        __syncthreads();
    }
}

// ---------------- launcher ----------------
extern "C" void kernel_launch(void* const* d_in, const int* in_sizes, int n_in,
                              void* d_out, int out_size, void* d_ws, size_t ws_size,
                              hipStream_t stream)
{
    const float* buf_h = (const float*)d_in[0];
    const float* stk_h = (const float*)d_in[1];
    const float* out_h = (const float*)d_in[2];
    const float* act_h = (const float*)d_in[3];
    const float* W1    = (const float*)d_in[4];
    const float* b1    = (const float*)d_in[5];
    const float* W2    = (const float*)d_in[6];
    const float* b2    = (const float*)d_in[7];
    const void*  mask  = d_in[8];
    const int*   ra    = (const int*)d_in[9];
    float*       out   = (float*)d_out;

    // ws layout:
    //   [0,256)            : ctr (mask byte counters 0..3, flag count at [4])
    //   [256, 256+64K)     : flagged-row list (int[16384])
    //   then               : W1T hi bf16 [1024][4096], W1T lo bf16 [1024][4096]
    //   then               : hidden chunk buffer (f32)
    int* ctr = (int*)d_ws;
    int* flagList = (int*)((char*)d_ws + 256);
    unsigned short* Bh = (unsigned short*)((char*)d_ws + 256 + 65536);
    unsigned short* Bl = Bh + (size_t)KTOT * HD;
    const size_t fixed = 256 + 65536 + 2 * (size_t)KTOT * HD * sizeof(unsigned short);
    float* hidden = (float*)((char*)d_ws + fixed);

    hipMemsetAsync(d_ws, 0, 256, stream);
    detect_mask_kernel<<<64, 256, 0, stream>>>(
        (const unsigned int*)mask, BTOT * NACT / 4, ctr);
    w1_split_kernel<<<dim3(KTOT / 64, HD / 64), 256, 0, stream>>>(W1, Bh, Bl);

    // chunk rows so hidden fits in the workspace (multiple of 128)
    const size_t avail = (ws_size > fixed) ? (ws_size - fixed) : 0;
    long maxRows = (long)(avail / ((size_t)HD * sizeof(float)));
    int Bc;
    if (maxRows >= BTOT) Bc = BTOT;
    else {
        Bc = (int)((maxRows / 128) * 128);
        if (Bc <= 0) Bc = 128;
    }

    for (int r0 = 0; r0 < BTOT; r0 += Bc) {
        const int rows = (BTOT - r0 < Bc) ? (BTOT - r0) : Bc;   // multiple of 128
        gemm1_mfma_kernel<<<dim3(8, rows / 128), 256, 0, stream>>>(
            buf_h, stk_h, out_h, act_h, Bh, Bl, b1, hidden, r0);
        head_kernel<<<rows / 4, 256, 0, stream>>>(
            hidden, W2, b2, mask, ra, ctr, flagList, out, r0);
    }

    refine_kernel<<<128, 256, 0, stream>>>(
        buf_h, stk_h, out_h, act_h, W1, b1, W2, b2, mask, ra, ctr, flagList, out);
}

// Round 3
// 1245.884 us; speedup vs baseline: 1.3958x; 1.1510x over previous
//
#include <hip/hip_runtime.h>
#include <math.h>

// TransitionNER head:  hidden = tanh(concat(4x[B,1024]) @ W1 + b1)
//                      logits = hidden @ W2 + b2 ; masked log-softmax ; argmax + gold gather
// B=16384, H=1024, A=20, K=4096.
//
// Round 3: pre-packed bf16 hi/lo tiles + pure-MFMA 3-pass GEMM.
//  - xpack/wpack: one-time f32 -> bf16 hi/lo split into swizzled 16KB tile images
//    (tile = [128 rows][8 slots of 16B: hi 0..3 | lo 4..7], phys slot = logical ^ (row&7)).
//  - gemm: BK=32 double-buffered LDS (64KB), global_load_lds width=16 (no staging VGPRs),
//    1 barrier/K-step, 48 MFMA/wave/step, XCD-chunked bijective block swizzle (n-inner).
//  - head flags masked top-2 gap < 1e-3; refine recomputes those rows in exact f32.

#define BTOT 16384
#define HD   1024
#define NACT 20
#define KTOT 4096
#define KT_N 128          // number of 32-wide k tiles

typedef __attribute__((ext_vector_type(8))) short short8;
typedef __attribute__((ext_vector_type(4))) float f32x4;

#define MFMA(a, b, c) __builtin_amdgcn_mfma_f32_16x16x32_bf16((a), (b), (c), 0, 0, 0)

// ---------------- global -> LDS direct load (16B) ----------------
__device__ __forceinline__ void gload16(const void* g, void* l)
{
    auto gp = (const __attribute__((address_space(1))) unsigned int*)((uintptr_t)g);
    auto lp = (__attribute__((address_space(3))) unsigned int*)((uintptr_t)l);
    __builtin_amdgcn_global_load_lds(gp, lp, 16, 0, 0);
}

// ---------------- bf16 split helpers (RNE) ----------------
__device__ __forceinline__ void split8(const float4 v0, const float4 v1,
                                       int4& hi, int4& lo)
{
    const float f[8] = {v0.x, v0.y, v0.z, v0.w, v1.x, v1.y, v1.z, v1.w};
    unsigned hp[4], lp[4];
#pragma unroll
    for (int i = 0; i < 4; ++i) {
        const unsigned u0 = __float_as_uint(f[2 * i]);
        const unsigned u1 = __float_as_uint(f[2 * i + 1]);
        const unsigned r0 = u0 + 0x7FFFu + ((u0 >> 16) & 1u);
        const unsigned r1 = u1 + 0x7FFFu + ((u1 >> 16) & 1u);
        hp[i] = (r0 >> 16) | (r1 & 0xFFFF0000u);
        const float h0 = __uint_as_float(r0 & 0xFFFF0000u);
        const float h1 = __uint_as_float(r1 & 0xFFFF0000u);
        const float d0 = f[2 * i] - h0;
        const float d1 = f[2 * i + 1] - h1;
        const unsigned s0 = __float_as_uint(d0);
        const unsigned s1 = __float_as_uint(d1);
        const unsigned q0 = s0 + 0x7FFFu + ((s0 >> 16) & 1u);
        const unsigned q1 = s1 + 0x7FFFu + ((s1 >> 16) & 1u);
        lp[i] = (q0 >> 16) | (q1 & 0xFFFF0000u);
    }
    hi = make_int4((int)hp[0], (int)hp[1], (int)hp[2], (int)hp[3]);
    lo = make_int4((int)lp[0], (int)lp[1], (int)lp[2], (int)lp[3]);
}

// ---------------- mask dtype detection ----------------
__global__ __launch_bounds__(256) void detect_mask_kernel(
    const unsigned int* __restrict__ w, int nwords, int* __restrict__ ctr)
{
    int c0 = 0, c1 = 0, c2 = 0, c3 = 0;
    for (int i = blockIdx.x * 256 + threadIdx.x; i < nwords; i += gridDim.x * 256) {
        unsigned int v = w[i];
        c0 += (v & 0x000000FFu) ? 1 : 0;
        c1 += (v & 0x0000FF00u) ? 1 : 0;
        c2 += (v & 0x00FF0000u) ? 1 : 0;
        c3 += (v & 0xFF000000u) ? 1 : 0;
    }
#pragma unroll
    for (int off = 32; off; off >>= 1) {
        c0 += __shfl_xor(c0, off, 64);
        c1 += __shfl_xor(c1, off, 64);
        c2 += __shfl_xor(c2, off, 64);
        c3 += __shfl_xor(c3, off, 64);
    }
    if ((threadIdx.x & 63) == 0) {
        atomicAdd(&ctr[0], c0);
        atomicAdd(&ctr[1], c1);
        atomicAdd(&ctr[2], c2);
        atomicAdd(&ctr[3], c3);
    }
}

// ---------------- X pack: f32 rows -> swizzled bf16 hi/lo tile images ----------------
// grid = (rows/128)*64 blocks; block handles (m-tile, 2 k-tiles).
__global__ __launch_bounds__(256) void xpack_kernel(
    const float* __restrict__ A0, const float* __restrict__ A1,
    const float* __restrict__ A2, const float* __restrict__ A3,
    char* __restrict__ Xp, int rowBase)
{
    const int b  = blockIdx.x;
    const int t  = threadIdx.x;
    const int mt = b >> 6;
    const int kt = ((b & 63) << 1) + (t >> 7);
    const int rr = t & 127;

    const int seg = kt >> 5;
    const float* __restrict__ s =
        (seg == 0) ? A0 : (seg == 1) ? A1 : (seg == 2) ? A2 : A3;
    const float4* sp = (const float4*)(s + (size_t)(rowBase + mt * 128 + rr) * HD
                                         + (kt & 31) * 32);

    int4 hi[4], lo[4];
#pragma unroll
    for (int c = 0; c < 4; ++c)
        split8(sp[2 * c], sp[2 * c + 1], hi[c], lo[c]);

    char* rowp = Xp + (((size_t)(mt * KT_N + kt)) << 14) + rr * 128;
    const int r7 = rr & 7;
#pragma unroll
    for (int c = 0; c < 4; ++c) {
        const int ph = (c ^ r7) << 4;
        *(int4*)(rowp + ph)        = hi[c];
        *(int4*)(rowp + (ph ^ 64)) = lo[c];
    }
}

// ---------------- W pack: [K][N] f32 -> swizzled bf16 hi/lo tile images ----------------
// grid = 8*128 blocks; block = (n-tile, k-tile); thread = (n-row, k-half).
__global__ __launch_bounds__(256) void wpack_kernel(
    const float* __restrict__ W1, char* __restrict__ Wp)
{
    const int b  = blockIdx.x;
    const int t  = threadIdx.x;
    const int nt = b >> 7;
    const int kt = b & 127;
    const int nn = t & 127;
    const int h  = t >> 7;

    float f[16];
#pragma unroll
    for (int kk = 0; kk < 16; ++kk)
        f[kk] = W1[(size_t)(kt * 32 + h * 16 + kk) * HD + nt * 128 + nn];

    int4 hi0, lo0, hi1, lo1;
    split8(make_float4(f[0], f[1], f[2], f[3]),
           make_float4(f[4], f[5], f[6], f[7]), hi0, lo0);
    split8(make_float4(f[8], f[9], f[10], f[11]),
           make_float4(f[12], f[13], f[14], f[15]), hi1, lo1);

    char* rowp = Wp + (((size_t)(nt * KT_N + kt)) << 14) + nn * 128;
    const int r7 = nn & 7;
    const int s0 = ((2 * h) ^ r7) << 4;
    const int s1 = ((2 * h + 1) ^ r7) << 4;
    *(int4*)(rowp + s0)        = hi0;
    *(int4*)(rowp + s1)        = hi1;
    *(int4*)(rowp + (s0 ^ 64)) = lo0;
    *(int4*)(rowp + (s1 ^ 64)) = lo1;
}

// ---------------- GEMM1 (pure MFMA, 3-pass) + bias + tanh ----------------
// nwg = mtiles*8; XCD-chunked bijective swizzle, n-inner within XCD.
__global__ __launch_bounds__(256, 2) void gemm1_mfma_kernel(
    const char* __restrict__ Xp, const char* __restrict__ Wp,
    const float* __restrict__ b1, float* __restrict__ hidden)
{
    __shared__ __align__(16) char smem[65536];   // 2 buf x (A 16KB + B 16KB)

    const int nwg = gridDim.x;
    const int q = nwg >> 3;
    const int newbid = (blockIdx.x & 7) * q + (blockIdx.x >> 3);
    const int mt = newbid >> 3;
    const int nt = newbid & 7;

    const int t    = threadIdx.x;
    const int lane = t & 63;
    const int wid  = t >> 6;
    const int wr = wid >> 1, wc = wid & 1;
    const int lrow = lane & 15;
    const int lk   = lane >> 4;

    const char* gA = Xp + (((size_t)mt * KT_N) << 14);
    const char* gB = Wp + (((size_t)nt * KT_N) << 14);

    // per-thread staging offsets (4 x 16B per tile)
    const int so0 = t << 4;

    // frag byte offsets within a 16KB tile image
    const unsigned aOff = (unsigned)(wr * 64 + lrow) * 128 + (((unsigned)lk ^ (unsigned)(lrow & 7)) << 4);
    const unsigned bOff = (unsigned)(wc * 64 + lrow) * 128 + (((unsigned)lk ^ (unsigned)(lrow & 7)) << 4);

    f32x4 acc[4][4];
#pragma unroll
    for (int i = 0; i < 4; ++i)
#pragma unroll
        for (int j = 0; j < 4; ++j) acc[i][j] = (f32x4){0.f, 0.f, 0.f, 0.f};

    // prologue: stage kt=0 into buf 0
#pragma unroll
    for (int i = 0; i < 4; ++i) {
        gload16(gA + so0 + i * 4096, smem + so0 + i * 4096);
        gload16(gB + so0 + i * 4096, smem + 16384 + so0 + i * 4096);
    }
    __syncthreads();

    int cur = 0;
    for (int kt = 0; kt < KT_N; ++kt) {
        // stage next k-tile into the other buffer (loads stay in flight through compute)
        if (kt + 1 < KT_N) {
            const char* nA = gA + (((size_t)(kt + 1)) << 14);
            const char* nB = gB + (((size_t)(kt + 1)) << 14);
            char* lA = smem + (cur ^ 1) * 32768;
            char* lB = lA + 16384;
#pragma unroll
            for (int i = 0; i < 4; ++i) {
                gload16(nA + so0 + i * 4096, lA + so0 + i * 4096);
                gload16(nB + so0 + i * 4096, lB + so0 + i * 4096);
            }
        }

        const char* lA = smem + cur * 32768;
        const char* lB = lA + 16384;

        short8 ah[4], al[4], bh[4], bl[4];
#pragma unroll
        for (int f = 0; f < 4; ++f) {
            ah[f] = *(const short8*)(lA + (aOff + f * 2048));
            al[f] = *(const short8*)(lA + ((aOff + f * 2048) ^ 64));
            bh[f] = *(const short8*)(lB + (bOff + f * 2048));
            bl[f] = *(const short8*)(lB + ((bOff + f * 2048) ^ 64));
        }
#pragma unroll
        for (int fi = 0; fi < 4; ++fi)
#pragma unroll
            for (int fj = 0; fj < 4; ++fj)
                acc[fi][fj] = MFMA(ah[fi], bh[fj], acc[fi][fj]);
#pragma unroll
        for (int fi = 0; fi < 4; ++fi)
#pragma unroll
            for (int fj = 0; fj < 4; ++fj)
                acc[fi][fj] = MFMA(ah[fi], bl[fj], acc[fi][fj]);
#pragma unroll
        for (int fi = 0; fi < 4; ++fi)
#pragma unroll
            for (int fj = 0; fj < 4; ++fj)
                acc[fi][fj] = MFMA(al[fi], bh[fj], acc[fi][fj]);

        __syncthreads();   // drains vmcnt (next-tile stage) + protects cur buffer
        cur ^= 1;
    }

    // epilogue: bias + tanh (D: col=lane&15, row=(lane>>4)*4+reg — m89-verified)
#pragma unroll
    for (int fj = 0; fj < 4; ++fj) {
        const int col = nt * 128 + wc * 64 + fj * 16 + lrow;
        const float bias = b1[col];
#pragma unroll
        for (int fi = 0; fi < 4; ++fi) {
            const int row0 = mt * 128 + wr * 64 + fi * 16 + lk * 4;
#pragma unroll
            for (int r = 0; r < 4; ++r)
                hidden[(size_t)(row0 + r) * HD + col] = tanhf(acc[fi][fj][r] + bias);
        }
    }
}

// ---------------- shared head/refine epilogue ----------------
__device__ __forceinline__ void finish_row(
    const float* __restrict__ acc, const float* __restrict__ b2,
    const void* __restrict__ mask, const int* __restrict__ real_actions,
    int fmt, int row, float* __restrict__ out,
    int* __restrict__ flagCnt, int* __restrict__ flagList, int lane)
{
    float masked[NACT];
#pragma unroll
    for (int a = 0; a < NACT; ++a) {
        const float lg = acc[a] + b2[a];
        bool valid;
        if (fmt == 0)      valid = ((const unsigned char*)mask)[(size_t)row * NACT + a] != 0;
        else if (fmt == 1) valid = ((const int*)mask)[(size_t)row * NACT + a] != 0;
        else               valid = ((const float*)mask)[(size_t)row * NACT + a] != 0.f;
        masked[a] = valid ? lg : -1e9f;
    }
    float m = masked[0], m2 = -3e38f;
    int amax = 0;
#pragma unroll
    for (int a = 1; a < NACT; ++a) {
        const float v = masked[a];
        if (v > m) { m2 = m; m = v; amax = a; }
        else if (v > m2) m2 = v;
    }
    float s = 0.f;
#pragma unroll
    for (int a = 0; a < NACT; ++a) s += expf(masked[a] - m);
    const float lse = m + logf(s);
    const int ga = real_actions[row];
    float gl = masked[0];
#pragma unroll
    for (int a = 1; a < NACT; ++a) gl = (ga == a) ? masked[a] : gl;
    if (lane == 0) {
        out[row] = (float)amax;
        out[BTOT + row] = gl - lse;
        if (flagList != nullptr && (m - m2) < 1e-3f) {
            const int ix = atomicAdd(flagCnt, 1);
            flagList[ix] = row;
        }
    }
}

// ---------------- head: logits, masked log-softmax, argmax, loss, gap-flag ----------------
__global__ __launch_bounds__(256) void head_kernel(
    const float* __restrict__ hidden, const float* __restrict__ W2,
    const float* __restrict__ b2, const void* __restrict__ mask,
    const int* __restrict__ real_actions, int* __restrict__ ctr,
    int* __restrict__ flagList, float* __restrict__ out, int rowBase)
{
    const int lane     = threadIdx.x & 63;
    const int localRow = blockIdx.x * 4 + (threadIdx.x >> 6);
    const int row      = rowBase + localRow;

    float acc[NACT];
#pragma unroll
    for (int a = 0; a < NACT; ++a) acc[a] = 0.f;

    const float* hrow = hidden + (size_t)localRow * HD;
#pragma unroll 4
    for (int j = 0; j < 16; ++j) {
        const int h = lane + 64 * j;
        const float hv = hrow[h];
        const float4* w4 = (const float4*)(W2 + (size_t)h * NACT);
        const float4 w0 = w4[0], w1 = w4[1], w2 = w4[2], w3 = w4[3], w4v = w4[4];
        acc[0]  = fmaf(hv, w0.x,  acc[0]);  acc[1]  = fmaf(hv, w0.y,  acc[1]);
        acc[2]  = fmaf(hv, w0.z,  acc[2]);  acc[3]  = fmaf(hv, w0.w,  acc[3]);
        acc[4]  = fmaf(hv, w1.x,  acc[4]);  acc[5]  = fmaf(hv, w1.y,  acc[5]);
        acc[6]  = fmaf(hv, w1.z,  acc[6]);  acc[7]  = fmaf(hv, w1.w,  acc[7]);
        acc[8]  = fmaf(hv, w2.x,  acc[8]);  acc[9]  = fmaf(hv, w2.y,  acc[9]);
        acc[10] = fmaf(hv, w2.z,  acc[10]); acc[11] = fmaf(hv, w2.w,  acc[11]);
        acc[12] = fmaf(hv, w3.x,  acc[12]); acc[13] = fmaf(hv, w3.y,  acc[13]);
        acc[14] = fmaf(hv, w3.z,  acc[14]); acc[15] = fmaf(hv, w3.w,  acc[15]);
        acc[16] = fmaf(hv, w4v.x, acc[16]); acc[17] = fmaf(hv, w4v.y, acc[17]);
        acc[18] = fmaf(hv, w4v.z, acc[18]); acc[19] = fmaf(hv, w4v.w, acc[19]);
    }
#pragma unroll
    for (int off = 32; off; off >>= 1) {
#pragma unroll
        for (int a = 0; a < NACT; ++a) acc[a] += __shfl_xor(acc[a], off, 64);
    }

    const int c1 = ctr[1], c2 = ctr[2], c3 = ctr[3];
    const int fmt = (c1 > 0) ? 0 : ((c2 > 0 || c3 > 0) ? 2 : 1);

    finish_row(acc, b2, mask, real_actions, fmt, row, out, &ctr[4], flagList, lane);
}

// ---------------- exact-f32 refinement of flagged rows (4 rows / block) ----------------
__global__ __launch_bounds__(256) void refine_kernel(
    const float* __restrict__ A0, const float* __restrict__ A1,
    const float* __restrict__ A2, const float* __restrict__ A3,
    const float* __restrict__ W1, const float* __restrict__ b1,
    const float* __restrict__ W2, const float* __restrict__ b2,
    const void* __restrict__ mask, const int* __restrict__ real_actions,
    const int* __restrict__ ctr, const int* __restrict__ list,
    float* __restrict__ out)
{
    __shared__ float xs[4][KTOT];   // 64 KiB, reused for hidden rows after k-loop
    const int tid = threadIdx.x;
    const int count = ctr[4];
    const int c1 = ctr[1], c2 = ctr[2], c3 = ctr[3];
    const int fmt = (c1 > 0) ? 0 : ((c2 > 0 || c3 > 0) ? 2 : 1);

    for (int base = blockIdx.x * 4; base < count; base += gridDim.x * 4) {
        const int nr = min(count - base, 4);
        for (int j = 0; j < nr; ++j) {
            const int row = list[base + j];
            for (int i = tid; i < KTOT; i += 256) {
                const float* seg = (i < 1024) ? A0 : (i < 2048) ? A1 : (i < 3072) ? A2 : A3;
                xs[j][i] = seg[(size_t)row * HD + (i & 1023)];
            }
        }
        __syncthreads();

        const int c0 = tid * 4;
        float acc[4][4];
#pragma unroll
        for (int j = 0; j < 4; ++j)
#pragma unroll
            for (int i = 0; i < 4; ++i) acc[j][i] = 0.f;

        for (int k = 0; k < KTOT; ++k) {
            const float4 w = *(const float4*)(W1 + (size_t)k * HD + c0);
#pragma unroll
            for (int j = 0; j < 4; ++j) {
                const float x = xs[j][k];
                acc[j][0] = fmaf(x, w.x, acc[j][0]);
                acc[j][1] = fmaf(x, w.y, acc[j][1]);
                acc[j][2] = fmaf(x, w.z, acc[j][2]);
                acc[j][3] = fmaf(x, w.w, acc[j][3]);
            }
        }
        __syncthreads();

        float* hs = &xs[0][0];      // [4][HD]
        const float4 bb = *(const float4*)(b1 + c0);
#pragma unroll
        for (int j = 0; j < 4; ++j) {
            hs[(size_t)j * HD + c0 + 0] = tanhf(acc[j][0] + bb.x);
            hs[(size_t)j * HD + c0 + 1] = tanhf(acc[j][1] + bb.y);
            hs[(size_t)j * HD + c0 + 2] = tanhf(acc[j][2] + bb.z);
            hs[(size_t)j * HD + c0 + 3] = tanhf(acc[j][3] + bb.w);
        }
        __syncthreads();

        const int j = tid >> 6, lane = tid & 63;
        if (j < nr) {
            const int row = list[base + j];
            float a20[NACT];
#pragma unroll
            for (int a = 0; a < NACT; ++a) a20[a] = 0.f;
#pragma unroll 4
            for (int m = 0; m < 16; ++m) {
                const int h = lane + 64 * m;
                const float hv = hs[(size_t)j * HD + h];
                const float4* w4 = (const float4*)(W2 + (size_t)h * NACT);
                const float4 w0 = w4[0], w1 = w4[1], w2 = w4[2], w3 = w4[3], w4v = w4[4];
                a20[0]  = fmaf(hv, w0.x,  a20[0]);  a20[1]  = fmaf(hv, w0.y,  a20[1]);
                a20[2]  = fmaf(hv, w0.z,  a20[2]);  a20[3]  = fmaf(hv, w0.w,  a20[3]);
                a20[4]  = fmaf(hv, w1.x,  a20[4]);  a20[5]  = fmaf(hv, w1.y,  a20[5]);
                a20[6]  = fmaf(hv, w1.z,  a20[6]);  a20[7]  = fmaf(hv, w1.w,  a20[7]);
                a20[8]  = fmaf(hv, w2.x,  a20[8]);  a20[9]  = fmaf(hv, w2.y,  a20[9]);
                a20[10] = fmaf(hv, w2.z,  a20[10]); a20[11] = fmaf(hv, w2.w,  a20[11]);
                a20[12] = fmaf(hv, w3.x,  a20[12]); a20[13] = fmaf(hv, w3.y,  a20[13]);
                a20[14] = fmaf(hv, w3.z,  a20[14]); a20[15] = fmaf(hv, w3.w,  a20[15]);
                a20[16] = fmaf(hv, w4v.x, a20[16]); a20[17] = fmaf(hv, w4v.y, a20[17]);
                a20[18] = fmaf(hv, w4v.z, a20[18]); a20[19] = fmaf(hv, w4v.w, a20[19]);
            }
#pragma unroll
            for (int off = 32; off; off >>= 1) {
#pragma unroll
                for (int a = 0; a < NACT; ++a) a20[a] += __shfl_xor(a20[a], off, 64);
            }
            finish_row(a20, b2, mask, real_actions, fmt, row, out, nullptr, nullptr, lane);
        }
        __syncthreads();
    }
}

// ---------------- launcher ----------------
extern "C" void kernel_launch(void* const* d_in, const int* in_sizes, int n_in,
                              void* d_out, int out_size, void* d_ws, size_t ws_size,
                              hipStream_t stream)
{
    const float* buf_h = (const float*)d_in[0];
    const float* stk_h = (const float*)d_in[1];
    const float* out_h = (const float*)d_in[2];
    const float* act_h = (const float*)d_in[3];
    const float* W1    = (const float*)d_in[4];
    const float* b1    = (const float*)d_in[5];
    const float* W2    = (const float*)d_in[6];
    const float* b2    = (const float*)d_in[7];
    const void*  mask  = d_in[8];
    const int*   ra    = (const int*)d_in[9];
    float*       out   = (float*)d_out;

    // ws layout:
    //   [0,256)          : ctr (mask byte counters 0..3, flag count at [4])
    //   [256, 256+64K)   : flagged-row list (int[16384])
    //   then 16MB        : Wp tile images (8 nt x 128 kt x 16KB)
    //   then             : Xp chunk tile images (16KB per row)
    //   then             : hidden chunk buffer (4KB per row)
    int*  ctr      = (int*)d_ws;
    int*  flagList = (int*)((char*)d_ws + 256);
    char* Wp       = (char*)d_ws + 256 + 65536;
    const size_t wpBytes = (size_t)8 * KT_N * 16384;           // 16 MiB
    char* XpBase   = Wp + wpBytes;
    const size_t fixed = 256 + 65536 + wpBytes;

    hipMemsetAsync(d_ws, 0, 256, stream);
    detect_mask_kernel<<<64, 256, 0, stream>>>(
        (const unsigned int*)mask, BTOT * NACT / 4, ctr);
    wpack_kernel<<<8 * KT_N, 256, 0, stream>>>(W1, Wp);

    // chunk rows so Xp (16KB/row) + hidden (4KB/row) fit in the workspace
    const size_t perRow = 16384 + 4096;
    const size_t avail  = (ws_size > fixed) ? (ws_size - fixed) : 0;
    long maxRows = (long)(avail / perRow);
    int Bc;
    if (maxRows >= BTOT) Bc = BTOT;
    else {
        Bc = (int)((maxRows / 128) * 128);
        if (Bc <= 0) Bc = 128;
    }
    float* hidden = (float*)(XpBase + (size_t)Bc * 16384);

    for (int r0 = 0; r0 < BTOT; r0 += Bc) {
        const int rows = (BTOT - r0 < Bc) ? (BTOT - r0) : Bc;   // multiple of 128
        const int mtiles = rows / 128;
        xpack_kernel<<<mtiles * 64, 256, 0, stream>>>(
            buf_h, stk_h, out_h, act_h, XpBase, r0);
        gemm1_mfma_kernel<<<mtiles * 8, 256, 0, stream>>>(
            XpBase, Wp, b1, hidden);
        head_kernel<<<rows / 4, 256, 0, stream>>>(
            hidden, W2, b2, mask, ra, ctr, flagList, out, r0);
    }

    refine_kernel<<<128, 256, 0, stream>>>(
        buf_h, stk_h, out_h, act_h, W1, b1, W2, b2, mask, ra, ctr, flagList, out);
}

// Round 4
// 1048.558 us; speedup vs baseline: 1.6584x; 1.1882x over previous
//
#include <hip/hip_runtime.h>
#include <math.h>

// TransitionNER head:  hidden = tanh(concat(4x[B,1024]) @ W1 + b1)
//                      logits = hidden @ W2 + b2 ; masked log-softmax ; argmax + gold gather
// B=16384, H=1024, A=20, K=4096.
//
// Round 4: fix refine_kernel latency chain (was 600us at 0.7% occupancy:
// one un-unrolled W1 load per k-iteration = 4096 serial memory latencies).
// Now: k-loop unrolled x8, 8 independent float4 loads batched ahead of the
// 128 FMAs -> latency hidden, ~55us compute floor per block.
// gemm/xpack/wpack/head unchanged from round 3.

#define BTOT 16384
#define HD   1024
#define NACT 20
#define KTOT 4096
#define KT_N 128          // number of 32-wide k tiles

typedef __attribute__((ext_vector_type(8))) short short8;
typedef __attribute__((ext_vector_type(4))) float f32x4;

#define MFMA(a, b, c) __builtin_amdgcn_mfma_f32_16x16x32_bf16((a), (b), (c), 0, 0, 0)

// ---------------- global -> LDS direct load (16B) ----------------
__device__ __forceinline__ void gload16(const void* g, void* l)
{
    auto gp = (const __attribute__((address_space(1))) unsigned int*)((uintptr_t)g);
    auto lp = (__attribute__((address_space(3))) unsigned int*)((uintptr_t)l);
    __builtin_amdgcn_global_load_lds(gp, lp, 16, 0, 0);
}

// ---------------- bf16 split helpers (RNE) ----------------
__device__ __forceinline__ void split8(const float4 v0, const float4 v1,
                                       int4& hi, int4& lo)
{
    const float f[8] = {v0.x, v0.y, v0.z, v0.w, v1.x, v1.y, v1.z, v1.w};
    unsigned hp[4], lp[4];
#pragma unroll
    for (int i = 0; i < 4; ++i) {
        const unsigned u0 = __float_as_uint(f[2 * i]);
        const unsigned u1 = __float_as_uint(f[2 * i + 1]);
        const unsigned r0 = u0 + 0x7FFFu + ((u0 >> 16) & 1u);
        const unsigned r1 = u1 + 0x7FFFu + ((u1 >> 16) & 1u);
        hp[i] = (r0 >> 16) | (r1 & 0xFFFF0000u);
        const float h0 = __uint_as_float(r0 & 0xFFFF0000u);
        const float h1 = __uint_as_float(r1 & 0xFFFF0000u);
        const float d0 = f[2 * i] - h0;
        const float d1 = f[2 * i + 1] - h1;
        const unsigned s0 = __float_as_uint(d0);
        const unsigned s1 = __float_as_uint(d1);
        const unsigned q0 = s0 + 0x7FFFu + ((s0 >> 16) & 1u);
        const unsigned q1 = s1 + 0x7FFFu + ((s1 >> 16) & 1u);
        lp[i] = (q0 >> 16) | (q1 & 0xFFFF0000u);
    }
    hi = make_int4((int)hp[0], (int)hp[1], (int)hp[2], (int)hp[3]);
    lo = make_int4((int)lp[0], (int)lp[1], (int)lp[2], (int)lp[3]);
}

// ---------------- mask dtype detection ----------------
__global__ __launch_bounds__(256) void detect_mask_kernel(
    const unsigned int* __restrict__ w, int nwords, int* __restrict__ ctr)
{
    int c0 = 0, c1 = 0, c2 = 0, c3 = 0;
    for (int i = blockIdx.x * 256 + threadIdx.x; i < nwords; i += gridDim.x * 256) {
        unsigned int v = w[i];
        c0 += (v & 0x000000FFu) ? 1 : 0;
        c1 += (v & 0x0000FF00u) ? 1 : 0;
        c2 += (v & 0x00FF0000u) ? 1 : 0;
        c3 += (v & 0xFF000000u) ? 1 : 0;
    }
#pragma unroll
    for (int off = 32; off; off >>= 1) {
        c0 += __shfl_xor(c0, off, 64);
        c1 += __shfl_xor(c1, off, 64);
        c2 += __shfl_xor(c2, off, 64);
        c3 += __shfl_xor(c3, off, 64);
    }
    if ((threadIdx.x & 63) == 0) {
        atomicAdd(&ctr[0], c0);
        atomicAdd(&ctr[1], c1);
        atomicAdd(&ctr[2], c2);
        atomicAdd(&ctr[3], c3);
    }
}

// ---------------- X pack: f32 rows -> swizzled bf16 hi/lo tile images ----------------
// grid = (rows/128)*64 blocks; block handles (m-tile, 2 k-tiles).
__global__ __launch_bounds__(256) void xpack_kernel(
    const float* __restrict__ A0, const float* __restrict__ A1,
    const float* __restrict__ A2, const float* __restrict__ A3,
    char* __restrict__ Xp, int rowBase)
{
    const int b  = blockIdx.x;
    const int t  = threadIdx.x;
    const int mt = b >> 6;
    const int kt = ((b & 63) << 1) + (t >> 7);
    const int rr = t & 127;

    const int seg = kt >> 5;
    const float* __restrict__ s =
        (seg == 0) ? A0 : (seg == 1) ? A1 : (seg == 2) ? A2 : A3;
    const float4* sp = (const float4*)(s + (size_t)(rowBase + mt * 128 + rr) * HD
                                         + (kt & 31) * 32);

    int4 hi[4], lo[4];
#pragma unroll
    for (int c = 0; c < 4; ++c)
        split8(sp[2 * c], sp[2 * c + 1], hi[c], lo[c]);

    char* rowp = Xp + (((size_t)(mt * KT_N + kt)) << 14) + rr * 128;
    const int r7 = rr & 7;
#pragma unroll
    for (int c = 0; c < 4; ++c) {
        const int ph = (c ^ r7) << 4;
        *(int4*)(rowp + ph)        = hi[c];
        *(int4*)(rowp + (ph ^ 64)) = lo[c];
    }
}

// ---------------- W pack: [K][N] f32 -> swizzled bf16 hi/lo tile images ----------------
__global__ __launch_bounds__(256) void wpack_kernel(
    const float* __restrict__ W1, char* __restrict__ Wp)
{
    const int b  = blockIdx.x;
    const int t  = threadIdx.x;
    const int nt = b >> 7;
    const int kt = b & 127;
    const int nn = t & 127;
    const int h  = t >> 7;

    float f[16];
#pragma unroll
    for (int kk = 0; kk < 16; ++kk)
        f[kk] = W1[(size_t)(kt * 32 + h * 16 + kk) * HD + nt * 128 + nn];

    int4 hi0, lo0, hi1, lo1;
    split8(make_float4(f[0], f[1], f[2], f[3]),
           make_float4(f[4], f[5], f[6], f[7]), hi0, lo0);
    split8(make_float4(f[8], f[9], f[10], f[11]),
           make_float4(f[12], f[13], f[14], f[15]), hi1, lo1);

    char* rowp = Wp + (((size_t)(nt * KT_N + kt)) << 14) + nn * 128;
    const int r7 = nn & 7;
    const int s0 = ((2 * h) ^ r7) << 4;
    const int s1 = ((2 * h + 1) ^ r7) << 4;
    *(int4*)(rowp + s0)        = hi0;
    *(int4*)(rowp + s1)        = hi1;
    *(int4*)(rowp + (s0 ^ 64)) = lo0;
    *(int4*)(rowp + (s1 ^ 64)) = lo1;
}

// ---------------- GEMM1 (pure MFMA, 3-pass) + bias + tanh ----------------
__global__ __launch_bounds__(256, 2) void gemm1_mfma_kernel(
    const char* __restrict__ Xp, const char* __restrict__ Wp,
    const float* __restrict__ b1, float* __restrict__ hidden)
{
    __shared__ __align__(16) char smem[65536];   // 2 buf x (A 16KB + B 16KB)

    const int nwg = gridDim.x;
    const int q = nwg >> 3;
    const int newbid = (blockIdx.x & 7) * q + (blockIdx.x >> 3);
    const int mt = newbid >> 3;
    const int nt = newbid & 7;

    const int t    = threadIdx.x;
    const int lane = t & 63;
    const int wid  = t >> 6;
    const int wr = wid >> 1, wc = wid & 1;
    const int lrow = lane & 15;
    const int lk   = lane >> 4;

    const char* gA = Xp + (((size_t)mt * KT_N) << 14);
    const char* gB = Wp + (((size_t)nt * KT_N) << 14);

    const int so0 = t << 4;

    const unsigned aOff = (unsigned)(wr * 64 + lrow) * 128 + (((unsigned)lk ^ (unsigned)(lrow & 7)) << 4);
    const unsigned bOff = (unsigned)(wc * 64 + lrow) * 128 + (((unsigned)lk ^ (unsigned)(lrow & 7)) << 4);

    f32x4 acc[4][4];
#pragma unroll
    for (int i = 0; i < 4; ++i)
#pragma unroll
        for (int j = 0; j < 4; ++j) acc[i][j] = (f32x4){0.f, 0.f, 0.f, 0.f};

    // prologue: stage kt=0 into buf 0
#pragma unroll
    for (int i = 0; i < 4; ++i) {
        gload16(gA + so0 + i * 4096, smem + so0 + i * 4096);
        gload16(gB + so0 + i * 4096, smem + 16384 + so0 + i * 4096);
    }
    __syncthreads();

    int cur = 0;
    for (int kt = 0; kt < KT_N; ++kt) {
        if (kt + 1 < KT_N) {
            const char* nA = gA + (((size_t)(kt + 1)) << 14);
            const char* nB = gB + (((size_t)(kt + 1)) << 14);
            char* lA = smem + (cur ^ 1) * 32768;
            char* lB = lA + 16384;
#pragma unroll
            for (int i = 0; i < 4; ++i) {
                gload16(nA + so0 + i * 4096, lA + so0 + i * 4096);
                gload16(nB + so0 + i * 4096, lB + so0 + i * 4096);
            }
        }

        const char* lA = smem + cur * 32768;
        const char* lB = lA + 16384;

        short8 ah[4], al[4], bh[4], bl[4];
#pragma unroll
        for (int f = 0; f < 4; ++f) {
            ah[f] = *(const short8*)(lA + (aOff + f * 2048));
            al[f] = *(const short8*)(lA + ((aOff + f * 2048) ^ 64));
            bh[f] = *(const short8*)(lB + (bOff + f * 2048));
            bl[f] = *(const short8*)(lB + ((bOff + f * 2048) ^ 64));
        }
#pragma unroll
        for (int fi = 0; fi < 4; ++fi)
#pragma unroll
            for (int fj = 0; fj < 4; ++fj)
                acc[fi][fj] = MFMA(ah[fi], bh[fj], acc[fi][fj]);
#pragma unroll
        for (int fi = 0; fi < 4; ++fi)
#pragma unroll
            for (int fj = 0; fj < 4; ++fj)
                acc[fi][fj] = MFMA(ah[fi], bl[fj], acc[fi][fj]);
#pragma unroll
        for (int fi = 0; fi < 4; ++fi)
#pragma unroll
            for (int fj = 0; fj < 4; ++fj)
                acc[fi][fj] = MFMA(al[fi], bh[fj], acc[fi][fj]);

        __syncthreads();
        cur ^= 1;
    }

    // epilogue: bias + tanh
#pragma unroll
    for (int fj = 0; fj < 4; ++fj) {
        const int col = nt * 128 + wc * 64 + fj * 16 + lrow;
        const float bias = b1[col];
#pragma unroll
        for (int fi = 0; fi < 4; ++fi) {
            const int row0 = mt * 128 + wr * 64 + fi * 16 + lk * 4;
#pragma unroll
            for (int r = 0; r < 4; ++r)
                hidden[(size_t)(row0 + r) * HD + col] = tanhf(acc[fi][fj][r] + bias);
        }
    }
}

// ---------------- shared head/refine epilogue ----------------
__device__ __forceinline__ void finish_row(
    const float* __restrict__ acc, const float* __restrict__ b2,
    const void* __restrict__ mask, const int* __restrict__ real_actions,
    int fmt, int row, float* __restrict__ out,
    int* __restrict__ flagCnt, int* __restrict__ flagList, int lane)
{
    float masked[NACT];
#pragma unroll
    for (int a = 0; a < NACT; ++a) {
        const float lg = acc[a] + b2[a];
        bool valid;
        if (fmt == 0)      valid = ((const unsigned char*)mask)[(size_t)row * NACT + a] != 0;
        else if (fmt == 1) valid = ((const int*)mask)[(size_t)row * NACT + a] != 0;
        else               valid = ((const float*)mask)[(size_t)row * NACT + a] != 0.f;
        masked[a] = valid ? lg : -1e9f;
    }
    float m = masked[0], m2 = -3e38f;
    int amax = 0;
#pragma unroll
    for (int a = 1; a < NACT; ++a) {
        const float v = masked[a];
        if (v > m) { m2 = m; m = v; amax = a; }
        else if (v > m2) m2 = v;
    }
    float s = 0.f;
#pragma unroll
    for (int a = 0; a < NACT; ++a) s += expf(masked[a] - m);
    const float lse = m + logf(s);
    const int ga = real_actions[row];
    float gl = masked[0];
#pragma unroll
    for (int a = 1; a < NACT; ++a) gl = (ga == a) ? masked[a] : gl;
    if (lane == 0) {
        out[row] = (float)amax;
        out[BTOT + row] = gl - lse;
        if (flagList != nullptr && (m - m2) < 1e-3f) {
            const int ix = atomicAdd(flagCnt, 1);
            flagList[ix] = row;
        }
    }
}

// ---------------- head: logits, masked log-softmax, argmax, loss, gap-flag ----------------
__global__ __launch_bounds__(256) void head_kernel(
    const float* __restrict__ hidden, const float* __restrict__ W2,
    const float* __restrict__ b2, const void* __restrict__ mask,
    const int* __restrict__ real_actions, int* __restrict__ ctr,
    int* __restrict__ flagList, float* __restrict__ out, int rowBase)
{
    const int lane     = threadIdx.x & 63;
    const int localRow = blockIdx.x * 4 + (threadIdx.x >> 6);
    const int row      = rowBase + localRow;

    float acc[NACT];
#pragma unroll
    for (int a = 0; a < NACT; ++a) acc[a] = 0.f;

    const float* hrow = hidden + (size_t)localRow * HD;
#pragma unroll 4
    for (int j = 0; j < 16; ++j) {
        const int h = lane + 64 * j;
        const float hv = hrow[h];
        const float4* w4 = (const float4*)(W2 + (size_t)h * NACT);
        const float4 w0 = w4[0], w1 = w4[1], w2 = w4[2], w3 = w4[3], w4v = w4[4];
        acc[0]  = fmaf(hv, w0.x,  acc[0]);  acc[1]  = fmaf(hv, w0.y,  acc[1]);
        acc[2]  = fmaf(hv, w0.z,  acc[2]);  acc[3]  = fmaf(hv, w0.w,  acc[3]);
        acc[4]  = fmaf(hv, w1.x,  acc[4]);  acc[5]  = fmaf(hv, w1.y,  acc[5]);
        acc[6]  = fmaf(hv, w1.z,  acc[6]);  acc[7]  = fmaf(hv, w1.w,  acc[7]);
        acc[8]  = fmaf(hv, w2.x,  acc[8]);  acc[9]  = fmaf(hv, w2.y,  acc[9]);
        acc[10] = fmaf(hv, w2.z,  acc[10]); acc[11] = fmaf(hv, w2.w,  acc[11]);
        acc[12] = fmaf(hv, w3.x,  acc[12]); acc[13] = fmaf(hv, w3.y,  acc[13]);
        acc[14] = fmaf(hv, w3.z,  acc[14]); acc[15] = fmaf(hv, w3.w,  acc[15]);
        acc[16] = fmaf(hv, w4v.x, acc[16]); acc[17] = fmaf(hv, w4v.y, acc[17]);
        acc[18] = fmaf(hv, w4v.z, acc[18]); acc[19] = fmaf(hv, w4v.w, acc[19]);
    }
#pragma unroll
    for (int off = 32; off; off >>= 1) {
#pragma unroll
        for (int a = 0; a < NACT; ++a) acc[a] += __shfl_xor(acc[a], off, 64);
    }

    const int c1 = ctr[1], c2 = ctr[2], c3 = ctr[3];
    const int fmt = (c1 > 0) ? 0 : ((c2 > 0 || c3 > 0) ? 2 : 1);

    finish_row(acc, b2, mask, real_actions, fmt, row, out, &ctr[4], flagList, lane);
}

// ---------------- exact-f32 refinement of flagged rows (4 rows / block) ----------------
// K-loop unrolled x8: 8 independent float4 W1 loads batched ahead of 128 FMAs.
__global__ __launch_bounds__(256) void refine_kernel(
    const float* __restrict__ A0, const float* __restrict__ A1,
    const float* __restrict__ A2, const float* __restrict__ A3,
    const float* __restrict__ W1, const float* __restrict__ b1,
    const float* __restrict__ W2, const float* __restrict__ b2,
    const void* __restrict__ mask, const int* __restrict__ real_actions,
    const int* __restrict__ ctr, const int* __restrict__ list,
    float* __restrict__ out)
{
    __shared__ float xs[4][KTOT];   // 64 KiB, reused for hidden rows after k-loop
    const int tid = threadIdx.x;
    const int count = ctr[4];
    const int c1 = ctr[1], c2 = ctr[2], c3 = ctr[3];
    const int fmt = (c1 > 0) ? 0 : ((c2 > 0 || c3 > 0) ? 2 : 1);

    for (int base = blockIdx.x * 4; base < count; base += gridDim.x * 4) {
        const int nr = min(count - base, 4);
        for (int j = 0; j < nr; ++j) {
            const int row = list[base + j];
            for (int i = tid; i < KTOT; i += 256) {
                const float* seg = (i < 1024) ? A0 : (i < 2048) ? A1 : (i < 3072) ? A2 : A3;
                xs[j][i] = seg[(size_t)row * HD + (i & 1023)];
            }
        }
        __syncthreads();

        const int c0 = tid * 4;
        float4 acc[4];
#pragma unroll
        for (int j = 0; j < 4; ++j) acc[j] = make_float4(0.f, 0.f, 0.f, 0.f);

        for (int k0 = 0; k0 < KTOT; k0 += 8) {
            float4 w[8];
#pragma unroll
            for (int u = 0; u < 8; ++u)
                w[u] = *(const float4*)(W1 + (size_t)(k0 + u) * HD + c0);
#pragma unroll
            for (int u = 0; u < 8; ++u) {
#pragma unroll
                for (int j = 0; j < 4; ++j) {
                    const float x = xs[j][k0 + u];   // LDS broadcast
                    acc[j].x = fmaf(x, w[u].x, acc[j].x);
                    acc[j].y = fmaf(x, w[u].y, acc[j].y);
                    acc[j].z = fmaf(x, w[u].z, acc[j].z);
                    acc[j].w = fmaf(x, w[u].w, acc[j].w);
                }
            }
        }
        __syncthreads();

        float* hs = &xs[0][0];      // [4][HD]
        const float4 bb = *(const float4*)(b1 + c0);
#pragma unroll
        for (int j = 0; j < 4; ++j) {
            hs[(size_t)j * HD + c0 + 0] = tanhf(acc[j].x + bb.x);
            hs[(size_t)j * HD + c0 + 1] = tanhf(acc[j].y + bb.y);
            hs[(size_t)j * HD + c0 + 2] = tanhf(acc[j].z + bb.z);
            hs[(size_t)j * HD + c0 + 3] = tanhf(acc[j].w + bb.w);
        }
        __syncthreads();

        const int j = tid >> 6, lane = tid & 63;
        if (j < nr) {
            const int row = list[base + j];
            float a20[NACT];
#pragma unroll
            for (int a = 0; a < NACT; ++a) a20[a] = 0.f;
#pragma unroll 4
            for (int m = 0; m < 16; ++m) {
                const int h = lane + 64 * m;
                const float hv = hs[(size_t)j * HD + h];
                const float4* w4 = (const float4*)(W2 + (size_t)h * NACT);
                const float4 w0 = w4[0], w1 = w4[1], w2 = w4[2], w3 = w4[3], w4v = w4[4];
                a20[0]  = fmaf(hv, w0.x,  a20[0]);  a20[1]  = fmaf(hv, w0.y,  a20[1]);
                a20[2]  = fmaf(hv, w0.z,  a20[2]);  a20[3]  = fmaf(hv, w0.w,  a20[3]);
                a20[4]  = fmaf(hv, w1.x,  a20[4]);  a20[5]  = fmaf(hv, w1.y,  a20[5]);
                a20[6]  = fmaf(hv, w1.z,  a20[6]);  a20[7]  = fmaf(hv, w1.w,  a20[7]);
                a20[8]  = fmaf(hv, w2.x,  a20[8]);  a20[9]  = fmaf(hv, w2.y,  a20[9]);
                a20[10] = fmaf(hv, w2.z,  a20[10]); a20[11] = fmaf(hv, w2.w,  a20[11]);
                a20[12] = fmaf(hv, w3.x,  a20[12]); a20[13] = fmaf(hv, w3.y,  a20[13]);
                a20[14] = fmaf(hv, w3.z,  a20[14]); a20[15] = fmaf(hv, w3.w,  a20[15]);
                a20[16] = fmaf(hv, w4v.x, a20[16]); a20[17] = fmaf(hv, w4v.y, a20[17]);
                a20[18] = fmaf(hv, w4v.z, a20[18]); a20[19] = fmaf(hv, w4v.w, a20[19]);
            }
#pragma unroll
            for (int off = 32; off; off >>= 1) {
#pragma unroll
                for (int a = 0; a < NACT; ++a) a20[a] += __shfl_xor(a20[a], off, 64);
            }
            finish_row(a20, b2, mask, real_actions, fmt, row, out, nullptr, nullptr, lane);
        }
        __syncthreads();
    }
}

// ---------------- launcher ----------------
extern "C" void kernel_launch(void* const* d_in, const int* in_sizes, int n_in,
                              void* d_out, int out_size, void* d_ws, size_t ws_size,
                              hipStream_t stream)
{
    const float* buf_h = (const float*)d_in[0];
    const float* stk_h = (const float*)d_in[1];
    const float* out_h = (const float*)d_in[2];
    const float* act_h = (const float*)d_in[3];
    const float* W1    = (const float*)d_in[4];
    const float* b1    = (const float*)d_in[5];
    const float* W2    = (const float*)d_in[6];
    const float* b2    = (const float*)d_in[7];
    const void*  mask  = d_in[8];
    const int*   ra    = (const int*)d_in[9];
    float*       out   = (float*)d_out;

    // ws layout:
    //   [0,256)          : ctr (mask byte counters 0..3, flag count at [4])
    //   [256, 256+64K)   : flagged-row list (int[16384])
    //   then 16MB        : Wp tile images (8 nt x 128 kt x 16KB)
    //   then             : Xp chunk tile images (16KB per row)
    //   then             : hidden chunk buffer (4KB per row)
    int*  ctr      = (int*)d_ws;
    int*  flagList = (int*)((char*)d_ws + 256);
    char* Wp       = (char*)d_ws + 256 + 65536;
    const size_t wpBytes = (size_t)8 * KT_N * 16384;           // 16 MiB
    char* XpBase   = Wp + wpBytes;
    const size_t fixed = 256 + 65536 + wpBytes;

    hipMemsetAsync(d_ws, 0, 256, stream);
    detect_mask_kernel<<<64, 256, 0, stream>>>(
        (const unsigned int*)mask, BTOT * NACT / 4, ctr);
    wpack_kernel<<<8 * KT_N, 256, 0, stream>>>(W1, Wp);

    // chunk rows so Xp (16KB/row) + hidden (4KB/row) fit in the workspace
    const size_t perRow = 16384 + 4096;
    const size_t avail  = (ws_size > fixed) ? (ws_size - fixed) : 0;
    long maxRows = (long)(avail / perRow);
    int Bc;
    if (maxRows >= BTOT) Bc = BTOT;
    else {
        Bc = (int)((maxRows / 128) * 128);
        if (Bc <= 0) Bc = 128;
    }
    float* hidden = (float*)(XpBase + (size_t)Bc * 16384);

    for (int r0 = 0; r0 < BTOT; r0 += Bc) {
        const int rows = (BTOT - r0 < Bc) ? (BTOT - r0) : Bc;   // multiple of 128
        const int mtiles = rows / 128;
        xpack_kernel<<<mtiles * 64, 256, 0, stream>>>(
            buf_h, stk_h, out_h, act_h, XpBase, r0);
        gemm1_mfma_kernel<<<mtiles * 8, 256, 0, stream>>>(
            XpBase, Wp, b1, hidden);
        head_kernel<<<rows / 4, 256, 0, stream>>>(
            hidden, W2, b2, mask, ra, ctr, flagList, out, r0);
    }

    refine_kernel<<<128, 256, 0, stream>>>(
        buf_h, stk_h, out_h, act_h, W1, b1, W2, b2, mask, ra, ctr, flagList, out);
}